// Round 5
// baseline (205.148 us; speedup 1.0000x reference)
//
#include <hip/hip_runtime.h>
#include <stdint.h>

typedef unsigned short u16;
typedef __attribute__((ext_vector_type(8))) short bf16x8;
typedef __attribute__((ext_vector_type(4))) float f32x4;
typedef __attribute__((ext_vector_type(16))) float f32x16;
typedef __attribute__((ext_vector_type(4))) u16 us4;
typedef __attribute__((ext_vector_type(8))) u16 us8;

// ---------- helpers ----------
__device__ __forceinline__ u16 f2bf(float f) {
  union { float f; unsigned u; } v; v.f = f;
  unsigned r = v.u + 0x7fffu + ((v.u >> 16) & 1u);   // RNE
  return (u16)(r >> 16);
}

__device__ __forceinline__ float bf2f(u16 b) {
  union { float f; unsigned u; } v; v.u = ((unsigned)b) << 16;
  return v.f;
}

// pack two positive f32 -> bf16x2 in one v_perm (round-to-nearest via +0x8000)
__device__ __forceinline__ unsigned pkbf(float a, float b) {
  union { float f; unsigned u; } x, y; x.f = a; y.f = b;
  return __builtin_amdgcn_perm(y.u + 0x8000u, x.u + 0x8000u, 0x07060302u);
}

__device__ __forceinline__ float fast_exp2(float x) {
#if __has_builtin(__builtin_amdgcn_exp2f)
  return __builtin_amdgcn_exp2f(x);
#else
  return exp2f(x);
#endif
}

__device__ __forceinline__ void gld16(const void* g, void* l) {
  __builtin_amdgcn_global_load_lds(
      (const __attribute__((address_space(1))) void*)g,
      (__attribute__((address_space(3))) void*)l, 16, 0, 0);
}

// ---------- prep: fp32 -> bf16 convert ----------
__global__ void cvt_kernel(const float* __restrict__ in, u16* __restrict__ out, int n4) {
  int i = blockIdx.x * blockDim.x + threadIdx.x;
  if (i >= n4) return;
  f32x4 v = ((const f32x4*)in)[i];
  us4 r;
#pragma unroll
  for (int j = 0; j < 4; ++j) r[j] = f2bf(v[j]);
  ((us4*)out)[i] = r;
}

// ---------- prep: transpose-convert W [R][C] fp32 -> [C][R] bf16 ----------
__global__ void transw_kernel(const float* __restrict__ in, u16* __restrict__ out, int R, int C) {
  __shared__ u16 tile[32][33];
  const int tx = threadIdx.x & 31, ty = threadIdx.x >> 5;
  const int c0 = blockIdx.x * 32, r0 = blockIdx.y * 32;
#pragma unroll
  for (int j = 0; j < 4; ++j)
    tile[ty + j * 8][tx] = f2bf(in[(size_t)(r0 + ty + j * 8) * C + c0 + tx]);
  __syncthreads();
#pragma unroll
  for (int j = 0; j < 4; ++j)
    out[(size_t)(c0 + ty + j * 8) * R + r0 + tx] = tile[tx][ty + j * 8];
}

// ---------- QKV GEMM: [4096,1024]bf16 @ [3072,1024]bf16^T + bias ----------
// XCD-swizzled tiles. Epilogue: Qb/Kb [head][s][64] (8-chunk swizzle by s%8),
// Vt [head][64][2048] with PER-64-KEY 8-chunk swizzle by dim row (so attention
// can DMA-stage 64-key V tiles linearly). Q pre-scaled by 0.125*log2(e).
__global__ __launch_bounds__(256) void qkv_gemm_kernel(
    const u16* __restrict__ A, const u16* __restrict__ Bt, const float* __restrict__ bias,
    u16* __restrict__ Qb, u16* __restrict__ Kb, u16* __restrict__ Vtb) {
  __shared__ u16 sm[17408];   // staging: As[0..4095], Bs[4096..8191]; epilogue: Ct[128][136]
  u16* As = sm;
  u16* Bs = sm + 4096;
  const int tid = threadIdx.x;
  const int w = tid >> 6, l = tid & 63, quad = l >> 4, lanelo = l & 15;
  const int wr = w >> 1, wc = w & 1;
  const int flat = blockIdx.x + 32 * blockIdx.y;       // 0..767
  const int xcd = flat & 7, lid = flat >> 3;           // lid 0..95
  const long m0 = (long)((xcd >> 1) * 8 + (lid & 7)) * 128;   // m-tile 0..31
  const long n0 = (long)((xcd & 1) * 12 + (lid >> 3)) * 128;  // n-tile 0..23

  f32x4 acc[4][4];
#pragma unroll
  for (int i = 0; i < 4; ++i)
#pragma unroll
    for (int j = 0; j < 4; ++j) acc[i][j] = (f32x4){0.f, 0.f, 0.f, 0.f};

  const u16* ag = A + (m0 + w * 32 + (l >> 2)) * 1024 + (l & 3) * 8;
  const u16* bg = Bt + (n0 + w * 32 + (l >> 2)) * 1024 + (l & 3) * 8;
  u16* asl = As + w * 1024;
  u16* bsl = Bs + w * 1024;

  for (int kt = 0; kt < 32; ++kt) {
    const int ko = kt * 32;
    gld16(ag + ko, asl);
    gld16(ag + 16 * 1024 + ko, asl + 512);
    gld16(bg + ko, bsl);
    gld16(bg + 16 * 1024 + ko, bsl + 512);
    __syncthreads();
    bf16x8 af[4], bf[4];
#pragma unroll
    for (int mt = 0; mt < 4; ++mt)
      af[mt] = *(const bf16x8*)(As + (wr * 64 + mt * 16 + lanelo) * 32 + quad * 8);
#pragma unroll
    for (int nt = 0; nt < 4; ++nt)
      bf[nt] = *(const bf16x8*)(Bs + (wc * 64 + nt * 16 + lanelo) * 32 + quad * 8);
#pragma unroll
    for (int mt = 0; mt < 4; ++mt)
#pragma unroll
      for (int nt = 0; nt < 4; ++nt)
        acc[mt][nt] = __builtin_amdgcn_mfma_f32_16x16x32_bf16(af[mt], bf[nt], acc[mt][nt], 0, 0, 0);
    __syncthreads();
  }

  const int t = (int)(n0 >> 10);
  const float scl = (t == 0) ? 0.18033688011112042f : 1.0f;  // Q pre-scaled by 0.125*log2e

  float bias_v[4];
#pragma unroll
  for (int nt = 0; nt < 4; ++nt) bias_v[nt] = bias[n0 + wc * 64 + nt * 16 + lanelo];

  u16* Ct = sm;  // [128][136]
#pragma unroll
  for (int mt = 0; mt < 4; ++mt)
#pragma unroll
    for (int nt = 0; nt < 4; ++nt)
#pragma unroll
      for (int r = 0; r < 4; ++r)
        Ct[(wr * 64 + mt * 16 + quad * 4 + r) * 136 + wc * 64 + nt * 16 + lanelo] =
            f2bf((acc[mt][nt][r] + bias_v[nt]) * scl);
  __syncthreads();

  const int b = (int)(m0 >> 11);
  const int s0 = (int)(m0 & 2047);
  const int h0 = (int)((n0 & 1023) >> 6);

  if (t < 2) {
    u16* dst = (t == 0) ? Qb : Kb;
#pragma unroll
    for (int p = 0; p < 8; ++p) {
      const int hh = p >> 2;
      const int sl = (p & 3) * 32 + (tid >> 3);
      const int c8 = tid & 7;
      us8 v = *(const us8*)(Ct + sl * 136 + hh * 64 + c8 * 8);
      const int pos = (c8 + sl) & 7;                       // dim-chunk swizzle by row%8
      const size_t off = ((size_t)((b * 16 + h0 + hh) * 2048 + s0 + sl)) * 64 + pos * 8;
      *(us8*)(dst + off) = v;
    }
  } else {
#pragma unroll
    for (int p = 0; p < 8; ++p) {
      const int hh = p >> 2;
      const int dl = (p & 3) * 16 + (tid >> 4);
      const int c16 = tid & 15;
      us8 v;
#pragma unroll
      for (int j = 0; j < 8; ++j) v[j] = Ct[(c16 * 8 + j) * 136 + hh * 64 + dl];
      const int sub = c16 >> 3, c8 = c16 & 7;              // 64-key subtile + chunk
      const int pos = (c8 + dl) & 7;                       // key-chunk swizzle by dim row
      const size_t off = ((size_t)((b * 16 + h0 + hh) * 64 + dl)) * 2048 + s0 + sub * 64 + pos * 8;
      *(us8*)(Vtb + off) = v;
    }
  }
}

// ---------- flash attention: 64q x 64key tiles, 2 waves, 2048 blocks ----------
// fid-swizzle clusters 4 heads per XCD (K/V working set ~2MB < L2).
// S^T = K·Q^T; hi-half fix via ds_bpermute(lane^32); rowsum on VALU.
__global__ __launch_bounds__(128, 4) void attn_kernel(
    const u16* __restrict__ Qb, const u16* __restrict__ Kb,
    const u16* __restrict__ Vtb, u16* __restrict__ Op, float* __restrict__ lp) {
  __shared__ u16 Ks[4096];   // [key 64][dim 64]  8-chunk swizzled by key%8
  __shared__ u16 Vs[4096];   // [dim 64][key 64]  8-chunk swizzled by dim%8
  const int tid = threadIdx.x;
  const int w = tid >> 6, l = tid & 63;
  const int m = l & 31, hi = l >> 5;
  const int fid = blockIdx.x + 32 * (blockIdx.y + 32 * blockIdx.z);
  const int head = (fid & 7) + 8 * ((fid >> 3) & 3);   // same 4 heads stay on one XCD
  const int qt = (fid >> 5) & 31;                      // 0..31 (64-row q tiles)
  const int z = fid >> 10;                             // 0..1 key half
  const u16* Qh = Qb + (size_t)head * 2048 * 64;
  const u16* Kh = Kb + (size_t)head * 2048 * 64;
  const u16* Vh = Vtb + (size_t)head * 64 * 2048;
  const int permaddr = (l ^ 32) << 2;

  // Q fragments (valid as B-operand: same per-lane layout)
  const int qrow = qt * 64 + w * 32 + m;
  bf16x8 qf[4];
#pragma unroll
  for (int ks = 0; ks < 4; ++ks) {
    const int c = ks * 2 + hi;
    const int pos = (c + qrow) & 7;
    qf[ks] = *(const bf16x8*)(Qh + (size_t)qrow * 64 + pos * 8);
  }

  f32x16 o0, o1;
#pragma unroll
  for (int i = 0; i < 16; ++i) { o0[i] = 0.f; o1[i] = 0.f; }
  float sacc = 0.f;

  const u16* kbase = Kh + (size_t)(z * 1024) * 64;     // advances 4096/tile
  const u16* vbase = Vh + z * 1024;                    // advances 64/tile

  for (int t = 0; t < 16; ++t) {
#pragma unroll
    for (int j = 0; j < 4; ++j) {
      const int i = w * 4 + j;
      gld16(kbase + i * 512 + l * 8, &Ks[i * 512]);
    }
#pragma unroll
    for (int j = 0; j < 4; ++j) {
      const int i = w * 4 + j;
      const int dd = i * 8 + (l >> 3);
      gld16(vbase + (size_t)dd * 2048 + (l & 7) * 8, &Vs[i * 512]);
    }
    __syncthreads();

#pragma unroll
    for (int g = 0; g < 2; ++g) {
      f32x16 st;
#pragma unroll
      for (int i = 0; i < 16; ++i) st[i] = 0.f;
      const int key = g * 32 + m;
#pragma unroll
      for (int ks = 0; ks < 4; ++ks) {
        const int c = ks * 2 + hi;
        const int pos = (c + key) & 7;
        bf16x8 kf = *(const bf16x8*)(&Ks[key * 64 + pos * 8]);
        st = __builtin_amdgcn_mfma_f32_32x32x16_bf16(kf, qf[ks], st, 0, 0, 0);
      }

      float p[16];
#pragma unroll
      for (int r = 0; r < 16; ++r) p[r] = fast_exp2(st[r]);
#pragma unroll
      for (int r = 0; r < 16; ++r) sacc += p[r];   // all 16 regs share q=m, differ in key

      // pack reg-quads to bf16 dword pairs: quad q4 holds keys 8*q4 + 4*hi + 0..3
      unsigned L[8];
#pragma unroll
      for (int q4 = 0; q4 < 4; ++q4) {
        L[2 * q4] = pkbf(p[4 * q4], p[4 * q4 + 1]);
        L[2 * q4 + 1] = pkbf(p[4 * q4 + 2], p[4 * q4 + 3]);
      }

#pragma unroll
      for (int s = 0; s < 2; ++s) {
        const unsigned a0 = L[4 * s], a1 = L[4 * s + 1];     // quad 2s
        const unsigned b0 = L[4 * s + 2], b1 = L[4 * s + 3]; // quad 2s+1
        const unsigned s0 = hi ? a0 : b0;
        const unsigned s1 = hi ? a1 : b1;
        const unsigned r0 = (unsigned)__builtin_amdgcn_ds_bpermute(permaddr, (int)s0);
        const unsigned r1 = (unsigned)__builtin_amdgcn_ds_bpermute(permaddr, (int)s1);
        int4 fd;
        fd.x = (int)(hi ? r0 : a0);
        fd.y = (int)(hi ? r1 : a1);
        fd.z = (int)(hi ? b0 : r0);
        fd.w = (int)(hi ? b1 : r1);
        union { int4 i; bf16x8 v; } pu; pu.i = fd;
        const int c = g * 4 + s * 2 + hi;   // key chunk 0..7 for V B-operand
#pragma unroll
        for (int n = 0; n < 2; ++n) {
          const int d = n * 32 + m;
          const int pos = (c + d) & 7;
          bf16x8 vf = *(const bf16x8*)(&Vs[d * 64 + pos * 8]);
          if (n == 0) o0 = __builtin_amdgcn_mfma_f32_32x32x16_bf16(pu.v, vf, o0, 0, 0, 0);
          else        o1 = __builtin_amdgcn_mfma_f32_32x32x16_bf16(pu.v, vf, o1, 0, 0, 0);
        }
      }
    }
    __syncthreads();
    kbase += 4096;
    vbase += 64;
  }

  // l = own half + partner half (per q-row = lane's m)
  union { float f; int i; } sv; sv.f = sacc;
  union { float f; int i; } pv; pv.i = __builtin_amdgcn_ds_bpermute(permaddr, sv.i);
  const float ltot = sacc + pv.f;
  if (hi == 0)
    lp[(size_t)z * 65536 + (size_t)head * 2048 + qt * 64 + w * 32 + m] = ltot;

  // store unnormalized O partial (bf16) to Op[z][B,S,1024]
  const int b = head >> 4, h = head & 15;
  u16* Od = Op + (size_t)z * 4194304;
#pragma unroll
  for (int r = 0; r < 16; ++r) {
    const int qlocal = (r & 3) + 8 * (r >> 2) + 4 * hi;
    const size_t base =
        ((size_t)(b * 2048 + qt * 64 + w * 32 + qlocal)) * 1024 + h * 64;
    Od[base + m] = f2bf(o0[r]);
    Od[base + 32 + m] = f2bf(o1[r]);
  }
}

// ---------- combine: Ob = (Op0 + Op1) / (l0 + l1), bf16 out ----------
__global__ __launch_bounds__(128) void combine_kernel(
    const u16* __restrict__ Op, const float* __restrict__ lp, u16* __restrict__ Ob) {
  const int r = blockIdx.x;          // 0..4095
  const int tid = threadIdx.x;       // 0..127
  const int col = tid * 8;
  const int b = r >> 11, s = r & 2047, h = col >> 6;
  const size_t li = (size_t)(b * 16 + h) * 2048 + s;
  const float linv = 1.0f / (lp[li] + lp[65536 + li]);
  us8 v0 = *(const us8*)(Op + (size_t)r * 1024 + col);
  us8 v1 = *(const us8*)(Op + 4194304 + (size_t)r * 1024 + col);
  us8 o;
#pragma unroll
  for (int j = 0; j < 8; ++j)
    o[j] = f2bf((bf2f(v0[j]) + bf2f(v1[j])) * linv);
  *(us8*)(Ob + (size_t)r * 1024 + col) = o;
}

// ---------- proj GEMM: 64x64 tiles, 1024 blocks (4/CU), 32x32x16 MFMA ----------
__global__ __launch_bounds__(256) void proj_gemm_kernel(
    const u16* __restrict__ A, const u16* __restrict__ Bt,
    const float* __restrict__ bias, float* __restrict__ out) {
  __shared__ u16 sm[4096];   // As 64x32 (2048 u16) + Bs 64x32 (2048 u16)
  u16* As = sm;
  u16* Bs = sm + 2048;
  const int tid = threadIdx.x;
  const int w = tid >> 6, l = tid & 63;
  const int m = l & 31, hi = l >> 5;
  const int wy = w >> 1, wx = w & 1;
  const int flat = blockIdx.x + 64 * blockIdx.y;       // 0..1023
  const int xcd = flat & 7, lid = flat >> 3;           // lid 0..127
  const long m0 = (long)(xcd * 8 + (lid >> 4)) * 64;   // m-tile 0..63
  const long n0 = (long)(lid & 15) * 64;               // n-tile 0..15

  f32x16 acc;
#pragma unroll
  for (int i = 0; i < 16; ++i) acc[i] = 0.f;

  const u16* ag = A + (m0 + (tid >> 2)) * 1024 + (tid & 3) * 8;
  const u16* bg = Bt + (n0 + (tid >> 2)) * 1024 + (tid & 3) * 8;
  u16* asl = As + w * 512;
  u16* bsl = Bs + w * 512;

  for (int kt = 0; kt < 32; ++kt) {
    const int ko = kt * 32;
    gld16(ag + ko, asl);
    gld16(bg + ko, bsl);
    __syncthreads();
    bf16x8 af[2], bf[2];
#pragma unroll
    for (int ks = 0; ks < 2; ++ks) {
      af[ks] = *(const bf16x8*)(As + (wy * 32 + m) * 32 + ks * 16 + hi * 8);
      bf[ks] = *(const bf16x8*)(Bs + (wx * 32 + m) * 32 + ks * 16 + hi * 8);
    }
    acc = __builtin_amdgcn_mfma_f32_32x32x16_bf16(af[0], bf[0], acc, 0, 0, 0);
    acc = __builtin_amdgcn_mfma_f32_32x32x16_bf16(af[1], bf[1], acc, 0, 0, 0);
    __syncthreads();
  }

  const float bias_v = bias[n0 + wx * 32 + m];
#pragma unroll
  for (int r = 0; r < 16; ++r) {
    const size_t mm = m0 + wy * 32 + (r & 3) + 8 * (r >> 2) + 4 * hi;
    const size_t nn = n0 + wx * 32 + m;
    out[mm * 1024 + nn] = acc[r] + bias_v;
  }
}

// ---------- launch ----------
extern "C" void kernel_launch(void* const* d_in, const int* in_sizes, int n_in,
                              void* d_out, int out_size, void* d_ws, size_t ws_size,
                              hipStream_t stream) {
  const float* x = (const float*)d_in[0];
  const float* Wqkv = (const float*)d_in[1];
  const float* bqkv = (const float*)d_in[2];
  const float* Wproj = (const float*)d_in[3];
  const float* bproj = (const float*)d_in[4];
  float* out = (float*)d_out;
  char* ws = (char*)d_ws;

  // workspace layout (44.6 MB), lifetime-based aliasing:
  //  [ 0..8M)   Xb (dead after qkv) -> Op0 ; [8..16M) Wqkt (dead after qkv) -> Op1
  //  [16..24M)  Qb (dead after attn) -> Ob ; [24..32M) Kb ; [32..40M) Vtb
  //  [40..42M)  Wpt ; [42..42.5M) lp
  u16* Xb   = (u16*)(ws);
  u16* Op   = (u16*)(ws);                 // Op0 @0, Op1 @ +4194304 elems
  u16* Wqkt = (u16*)(ws + 8388608);
  u16* Qb   = (u16*)(ws + 16777216);
  u16* Ob   = (u16*)(ws + 16777216);
  u16* Kb   = (u16*)(ws + 25165824);
  u16* Vtb  = (u16*)(ws + 33554432);
  u16* Wpt  = (u16*)(ws + 41943040);
  float* lp = (float*)(ws + 44040192);

  cvt_kernel<<<4096, 256, 0, stream>>>(x, Xb, 1048576);
  transw_kernel<<<dim3(96, 32), 256, 0, stream>>>(Wqkv, Wqkt, 1024, 3072);
  transw_kernel<<<dim3(32, 32), 256, 0, stream>>>(Wproj, Wpt, 1024, 1024);
  qkv_gemm_kernel<<<dim3(32, 24), 256, 0, stream>>>(Xb, Wqkt, bqkv, Qb, Kb, Vtb);
  attn_kernel<<<dim3(32, 32, 2), 128, 0, stream>>>(Qb, Kb, Vtb, Op, lp);
  combine_kernel<<<4096, 128, 0, stream>>>(Op, lp, Ob);
  proj_gemm_kernel<<<dim3(64, 16), 256, 0, stream>>>(Ob, Wpt, bproj, out);
}

// Round 6
// 188.361 us; speedup vs baseline: 1.0891x; 1.0891x over previous
//
#include <hip/hip_runtime.h>
#include <stdint.h>

typedef unsigned short u16;
typedef __attribute__((ext_vector_type(8))) short bf16x8;
typedef __attribute__((ext_vector_type(4))) float f32x4;
typedef __attribute__((ext_vector_type(16))) float f32x16;
typedef __attribute__((ext_vector_type(4))) u16 us4;
typedef __attribute__((ext_vector_type(8))) u16 us8;

// ---------- helpers ----------
__device__ __forceinline__ u16 f2bf(float f) {
  union { float f; unsigned u; } v; v.f = f;
  unsigned r = v.u + 0x7fffu + ((v.u >> 16) & 1u);   // RNE
  return (u16)(r >> 16);
}

__device__ __forceinline__ float bf2f(u16 b) {
  union { float f; unsigned u; } v; v.u = ((unsigned)b) << 16;
  return v.f;
}

// pack two positive f32 -> bf16x2 in one v_perm (round-to-nearest via +0x8000)
__device__ __forceinline__ unsigned pkbf(float a, float b) {
  union { float f; unsigned u; } x, y; x.f = a; y.f = b;
  return __builtin_amdgcn_perm(y.u + 0x8000u, x.u + 0x8000u, 0x07060302u);
}

__device__ __forceinline__ float fast_exp2(float x) {
#if __has_builtin(__builtin_amdgcn_exp2f)
  return __builtin_amdgcn_exp2f(x);
#else
  return exp2f(x);
#endif
}

__device__ __forceinline__ void gld16(const void* g, void* l) {
  __builtin_amdgcn_global_load_lds(
      (const __attribute__((address_space(1))) void*)g,
      (__attribute__((address_space(3))) void*)l, 16, 0, 0);
}

// ---------- prep (merged): cvt x -> bf16; transpose-convert both W ----------
// blocks [0,4096): cvt. [4096,7168): W_qkv^T (96x32). [7168,8192): W_proj^T (32x32).
__global__ void prep_kernel(const float* __restrict__ x, u16* __restrict__ Xb,
                            const float* __restrict__ Wqkv, u16* __restrict__ Wqkt,
                            const float* __restrict__ Wproj, u16* __restrict__ Wpt) {
  __shared__ u16 tile[32][33];
  const int blk = blockIdx.x;
  if (blk < 4096) {
    const int i = blk * 256 + threadIdx.x;          // 4096*256 == 1048576 exactly
    f32x4 v = ((const f32x4*)x)[i];
    us4 r;
#pragma unroll
    for (int j = 0; j < 4; ++j) r[j] = f2bf(v[j]);
    ((us4*)Xb)[i] = r;
    return;
  }
  const float* in;
  u16* out;
  int R, C, t;
  if (blk < 7168) { in = Wqkv; out = Wqkt; R = 1024; C = 3072; t = blk - 4096; }
  else            { in = Wproj; out = Wpt; R = 1024; C = 1024; t = blk - 7168; }
  const int gx = (C == 3072) ? (t % 96) : (t % 32);
  const int gy = (C == 3072) ? (t / 96) : (t / 32);
  const int tx = threadIdx.x & 31, ty = threadIdx.x >> 5;
  const int c0 = gx * 32, r0 = gy * 32;
#pragma unroll
  for (int j = 0; j < 4; ++j)
    tile[ty + j * 8][tx] = f2bf(in[(size_t)(r0 + ty + j * 8) * C + c0 + tx]);
  __syncthreads();
#pragma unroll
  for (int j = 0; j < 4; ++j)
    out[(size_t)(c0 + ty + j * 8) * R + r0 + tx] = tile[tx][ty + j * 8];
}

// ---------- QKV GEMM: [4096,1024]bf16 @ [3072,1024]bf16^T + bias ----------
// XCD-swizzled tiles. Epilogue: Qb/Kb [head][s][64] (8-chunk swizzle by s%8),
// Vt [head][64][2048] (16-chunk swizzle by dim row, over 128-key tiles).
// Q pre-scaled by 0.125*log2(e).
__global__ __launch_bounds__(256) void qkv_gemm_kernel(
    const u16* __restrict__ A, const u16* __restrict__ Bt, const float* __restrict__ bias,
    u16* __restrict__ Qb, u16* __restrict__ Kb, u16* __restrict__ Vtb) {
  __shared__ u16 sm[17408];   // staging: As[0..4095], Bs[4096..8191]; epilogue: Ct[128][136]
  u16* As = sm;
  u16* Bs = sm + 4096;
  const int tid = threadIdx.x;
  const int w = tid >> 6, l = tid & 63, quad = l >> 4, lanelo = l & 15;
  const int wr = w >> 1, wc = w & 1;
  const int flat = blockIdx.x + 32 * blockIdx.y;       // 0..767
  const int xcd = flat & 7, lid = flat >> 3;           // lid 0..95
  const long m0 = (long)((xcd >> 1) * 8 + (lid & 7)) * 128;   // m-tile 0..31
  const long n0 = (long)((xcd & 1) * 12 + (lid >> 3)) * 128;  // n-tile 0..23

  f32x4 acc[4][4];
#pragma unroll
  for (int i = 0; i < 4; ++i)
#pragma unroll
    for (int j = 0; j < 4; ++j) acc[i][j] = (f32x4){0.f, 0.f, 0.f, 0.f};

  const u16* ag = A + (m0 + w * 32 + (l >> 2)) * 1024 + (l & 3) * 8;
  const u16* bg = Bt + (n0 + w * 32 + (l >> 2)) * 1024 + (l & 3) * 8;
  u16* asl = As + w * 1024;
  u16* bsl = Bs + w * 1024;

  for (int kt = 0; kt < 32; ++kt) {
    const int ko = kt * 32;
    gld16(ag + ko, asl);
    gld16(ag + 16 * 1024 + ko, asl + 512);
    gld16(bg + ko, bsl);
    gld16(bg + 16 * 1024 + ko, bsl + 512);
    __syncthreads();
    bf16x8 af[4], bf[4];
#pragma unroll
    for (int mt = 0; mt < 4; ++mt)
      af[mt] = *(const bf16x8*)(As + (wr * 64 + mt * 16 + lanelo) * 32 + quad * 8);
#pragma unroll
    for (int nt = 0; nt < 4; ++nt)
      bf[nt] = *(const bf16x8*)(Bs + (wc * 64 + nt * 16 + lanelo) * 32 + quad * 8);
#pragma unroll
    for (int mt = 0; mt < 4; ++mt)
#pragma unroll
      for (int nt = 0; nt < 4; ++nt)
        acc[mt][nt] = __builtin_amdgcn_mfma_f32_16x16x32_bf16(af[mt], bf[nt], acc[mt][nt], 0, 0, 0);
    __syncthreads();
  }

  const int t = (int)(n0 >> 10);
  const float scl = (t == 0) ? 0.18033688011112042f : 1.0f;  // Q pre-scaled by 0.125*log2e

  float bias_v[4];
#pragma unroll
  for (int nt = 0; nt < 4; ++nt) bias_v[nt] = bias[n0 + wc * 64 + nt * 16 + lanelo];

  u16* Ct = sm;  // [128][136]
#pragma unroll
  for (int mt = 0; mt < 4; ++mt)
#pragma unroll
    for (int nt = 0; nt < 4; ++nt)
#pragma unroll
      for (int r = 0; r < 4; ++r)
        Ct[(wr * 64 + mt * 16 + quad * 4 + r) * 136 + wc * 64 + nt * 16 + lanelo] =
            f2bf((acc[mt][nt][r] + bias_v[nt]) * scl);
  __syncthreads();

  const int b = (int)(m0 >> 11);
  const int s0 = (int)(m0 & 2047);
  const int h0 = (int)((n0 & 1023) >> 6);

  if (t < 2) {
    u16* dst = (t == 0) ? Qb : Kb;
#pragma unroll
    for (int p = 0; p < 8; ++p) {
      const int hh = p >> 2;
      const int sl = (p & 3) * 32 + (tid >> 3);
      const int c8 = tid & 7;
      us8 v = *(const us8*)(Ct + sl * 136 + hh * 64 + c8 * 8);
      const int pos = (c8 + sl) & 7;                       // dim-chunk swizzle by row%8
      const size_t off = ((size_t)((b * 16 + h0 + hh) * 2048 + s0 + sl)) * 64 + pos * 8;
      *(us8*)(dst + off) = v;
    }
  } else {
#pragma unroll
    for (int p = 0; p < 8; ++p) {
      const int hh = p >> 2;
      const int dl = (p & 3) * 16 + (tid >> 4);
      const int c16 = tid & 15;
      us8 v;
#pragma unroll
      for (int j = 0; j < 8; ++j) v[j] = Ct[(c16 * 8 + j) * 136 + hh * 64 + dl];
      const int pos = (c16 + dl) & 15;                     // key-chunk swizzle by dim row
      const size_t off = ((size_t)((b * 16 + h0 + hh) * 64 + dl)) * 2048 + s0 + pos * 8;
      *(us8*)(Vtb + off) = v;
    }
  }
}

// ---------- flash attention, 32x32x16 MFMA, key-split z=2 ----------
// 1024 blocks, fid-swizzled: 4 heads per XCD (K+V 2MB < 4MiB L2; FETCH win
// proven in r5). 256 threads, wave w -> 32 q rows. S^T = K·Q^T; hi-half
// mismatch fixed via ds_bpermute(lane^32); rowsum on VALU (r4 showed MFMA
// rowsum moves work onto the binding PV pipe).
__global__ __launch_bounds__(256, 4) void attn_kernel(
    const u16* __restrict__ Qb, const u16* __restrict__ Kb,
    const u16* __restrict__ Vtb, u16* __restrict__ Op, float* __restrict__ lp) {
  __shared__ u16 Ks[8192];   // [key 128][dim 64]  8-chunk swizzled
  __shared__ u16 Vs[8192];   // [dim 64][key 128] 16-chunk swizzled
  const int tid = threadIdx.x;
  const int w = tid >> 6, l = tid & 63;
  const int m = l & 31, hi = l >> 5;
  const int fid = blockIdx.x;
  const int head = (fid & 7) + 8 * ((fid >> 3) & 3);   // 4 heads stay on one XCD
  const int qt = (fid >> 5) & 15;
  const int z = fid >> 9;
  const u16* Qh = Qb + (size_t)head * 2048 * 64;
  const u16* Kh = Kb + (size_t)head * 2048 * 64;
  const u16* Vh = Vtb + (size_t)head * 64 * 2048;
  const int permaddr = (l ^ 32) << 2;

  // Q fragments (valid as B-operand: same per-lane layout)
  const int qrow = qt * 128 + w * 32 + m;
  bf16x8 qf[4];
#pragma unroll
  for (int ks = 0; ks < 4; ++ks) {
    const int c = ks * 2 + hi;
    const int pos = (c + qrow) & 7;
    qf[ks] = *(const bf16x8*)(Qh + (size_t)qrow * 64 + pos * 8);
  }

  f32x16 o0, o1;
#pragma unroll
  for (int i = 0; i < 16; ++i) { o0[i] = 0.f; o1[i] = 0.f; }
  float sacc = 0.f;

  for (int kt = 0; kt < 8; ++kt) {
    const int kb = z * 8 + kt;
    const u16* kbase = Kh + (size_t)kb * 8192;
#pragma unroll
    for (int j = 0; j < 4; ++j) {
      const int i = w * 4 + j;
      gld16(kbase + i * 512 + l * 8, &Ks[i * 512]);
    }
#pragma unroll
    for (int j = 0; j < 4; ++j) {
      const int i = w * 4 + j;
      const int dd = i * 4 + (l >> 4);
      gld16(Vh + (size_t)dd * 2048 + kb * 128 + (l & 15) * 8, &Vs[i * 512]);
    }
    __syncthreads();

#pragma unroll
    for (int g = 0; g < 4; ++g) {
      f32x16 st;
#pragma unroll
      for (int i = 0; i < 16; ++i) st[i] = 0.f;
      const int key = g * 32 + m;
#pragma unroll
      for (int ks = 0; ks < 4; ++ks) {
        const int c = ks * 2 + hi;
        const int pos = (c + key) & 7;
        bf16x8 kf = *(const bf16x8*)(&Ks[key * 64 + pos * 8]);
        st = __builtin_amdgcn_mfma_f32_32x32x16_bf16(kf, qf[ks], st, 0, 0, 0);
      }

      float p[16];
#pragma unroll
      for (int r = 0; r < 16; ++r) p[r] = fast_exp2(st[r]);
#pragma unroll
      for (int r = 0; r < 16; ++r) sacc += p[r];   // all regs share q=m, differ in key

      // pack reg-quads to bf16 dword pairs: quad q4 holds keys 8*q4 + 4*hi + 0..3
      unsigned L[8];
#pragma unroll
      for (int q4 = 0; q4 < 4; ++q4) {
        L[2 * q4] = pkbf(p[4 * q4], p[4 * q4 + 1]);
        L[2 * q4 + 1] = pkbf(p[4 * q4 + 2], p[4 * q4 + 3]);
      }

#pragma unroll
      for (int s = 0; s < 2; ++s) {
        const unsigned a0 = L[4 * s], a1 = L[4 * s + 1];     // quad 2s
        const unsigned b0 = L[4 * s + 2], b1 = L[4 * s + 3]; // quad 2s+1
        const unsigned s0 = hi ? a0 : b0;
        const unsigned s1 = hi ? a1 : b1;
        const unsigned r0 = (unsigned)__builtin_amdgcn_ds_bpermute(permaddr, (int)s0);
        const unsigned r1 = (unsigned)__builtin_amdgcn_ds_bpermute(permaddr, (int)s1);
        int4 fd;
        fd.x = (int)(hi ? r0 : a0);
        fd.y = (int)(hi ? r1 : a1);
        fd.z = (int)(hi ? b0 : r0);
        fd.w = (int)(hi ? b1 : r1);
        union { int4 i; bf16x8 v; } pu; pu.i = fd;
        const int c = g * 4 + s * 2 + hi;   // key chunk for V B-operand
#pragma unroll
        for (int n = 0; n < 2; ++n) {
          const int d = n * 32 + m;
          const int pos = (c + d) & 15;
          bf16x8 vf = *(const bf16x8*)(&Vs[d * 128 + pos * 8]);
          if (n == 0) o0 = __builtin_amdgcn_mfma_f32_32x32x16_bf16(pu.v, vf, o0, 0, 0, 0);
          else        o1 = __builtin_amdgcn_mfma_f32_32x32x16_bf16(pu.v, vf, o1, 0, 0, 0);
        }
      }
    }
    __syncthreads();
  }

  // l = own half + partner half
  union { float f; int i; } sv; sv.f = sacc;
  union { float f; int i; } pv; pv.i = __builtin_amdgcn_ds_bpermute(permaddr, sv.i);
  const float ltot = sacc + pv.f;
  if (hi == 0)
    lp[(size_t)z * 65536 + (size_t)head * 2048 + qt * 128 + w * 32 + m] = ltot;

  // store unnormalized O partial (bf16) to Op[z][B,S,1024]
  const int b = head >> 4, h = head & 15;
  u16* Od = Op + (size_t)z * 4194304;
#pragma unroll
  for (int r = 0; r < 16; ++r) {
    const int qlocal = (r & 3) + 8 * (r >> 2) + 4 * hi;
    const size_t base =
        ((size_t)(b * 2048 + qt * 128 + w * 32 + qlocal)) * 1024 + h * 64;
    Od[base + m] = f2bf(o0[r]);
    Od[base + 32 + m] = f2bf(o1[r]);
  }
}

// ---------- combine: Ob = (Op0 + Op1) / (l0 + l1), bf16 out ----------
__global__ __launch_bounds__(128) void combine_kernel(
    const u16* __restrict__ Op, const float* __restrict__ lp, u16* __restrict__ Ob) {
  const int r = blockIdx.x;          // 0..4095
  const int tid = threadIdx.x;       // 0..127
  const int col = tid * 8;
  const int b = r >> 11, s = r & 2047, h = col >> 6;
  const size_t li = (size_t)(b * 16 + h) * 2048 + s;
  const float linv = 1.0f / (lp[li] + lp[65536 + li]);
  us8 v0 = *(const us8*)(Op + (size_t)r * 1024 + col);
  us8 v1 = *(const us8*)(Op + 4194304 + (size_t)r * 1024 + col);
  us8 o;
#pragma unroll
  for (int j = 0; j < 8; ++j)
    o[j] = f2bf((bf2f(v0[j]) + bf2f(v1[j])) * linv);
  *(us8*)(Ob + (size_t)r * 1024 + col) = o;
}

// ---------- proj GEMM: 128x64 tiles, 512 blocks (2/CU), plain stores ----------
// XCD swizzle: each XCD covers 4 m-tiles x all n (A 1MB + B 2MB working set).
__global__ __launch_bounds__(256) void proj_gemm_kernel(
    const u16* __restrict__ A, const u16* __restrict__ Bt,
    const float* __restrict__ bias, float* __restrict__ out) {
  __shared__ u16 sm[6144];   // As 128x32 (4096) + Bs 64x32 (2048)
  u16* As = sm;
  u16* Bs = sm + 4096;
  const int tid = threadIdx.x;
  const int w = tid >> 6, l = tid & 63, quad = l >> 4, lanelo = l & 15;
  const int wr = w >> 1, wc = w & 1;
  const int flat = blockIdx.x + 32 * blockIdx.y;       // 0..511
  const int xcd = flat & 7, lid = flat >> 3;           // lid 0..63
  const long m0 = (long)(xcd * 4 + (lid & 3)) * 128;   // m-tile 0..31
  const long n0 = (long)(lid >> 2) * 64;               // n-tile 0..15

  f32x4 acc[4][2];
#pragma unroll
  for (int i = 0; i < 4; ++i)
#pragma unroll
    for (int j = 0; j < 2; ++j) acc[i][j] = (f32x4){0.f, 0.f, 0.f, 0.f};

  const u16* ag = A + (m0 + w * 32 + (l >> 2)) * 1024 + (l & 3) * 8;
  const u16* bg = Bt + (n0 + w * 16 + (l >> 2)) * 1024 + (l & 3) * 8;
  u16* asl = As + w * 1024;
  u16* bsl = Bs + w * 512;

  for (int kt = 0; kt < 32; ++kt) {
    const int ko = kt * 32;
    gld16(ag + ko, asl);
    gld16(ag + 16 * 1024 + ko, asl + 512);
    gld16(bg + ko, bsl);
    __syncthreads();
    bf16x8 af[4], bf[2];
#pragma unroll
    for (int mt = 0; mt < 4; ++mt)
      af[mt] = *(const bf16x8*)(As + (wr * 64 + mt * 16 + lanelo) * 32 + quad * 8);
#pragma unroll
    for (int nt = 0; nt < 2; ++nt)
      bf[nt] = *(const bf16x8*)(Bs + (wc * 32 + nt * 16 + lanelo) * 32 + quad * 8);
#pragma unroll
    for (int mt = 0; mt < 4; ++mt)
#pragma unroll
      for (int nt = 0; nt < 2; ++nt)
        acc[mt][nt] = __builtin_amdgcn_mfma_f32_16x16x32_bf16(af[mt], bf[nt], acc[mt][nt], 0, 0, 0);
    __syncthreads();
  }

  float bias_v[2];
#pragma unroll
  for (int nt = 0; nt < 2; ++nt)
    bias_v[nt] = bias[n0 + wc * 32 + nt * 16 + lanelo];

#pragma unroll
  for (int mt = 0; mt < 4; ++mt)
#pragma unroll
    for (int nt = 0; nt < 2; ++nt)
#pragma unroll
      for (int r = 0; r < 4; ++r) {
        const size_t mm = m0 + wr * 64 + mt * 16 + quad * 4 + r;
        const size_t nn = n0 + wc * 32 + nt * 16 + lanelo;
        out[mm * 1024 + nn] = acc[mt][nt][r] + bias_v[nt];
      }
}

// ---------- launch ----------
extern "C" void kernel_launch(void* const* d_in, const int* in_sizes, int n_in,
                              void* d_out, int out_size, void* d_ws, size_t ws_size,
                              hipStream_t stream) {
  const float* x = (const float*)d_in[0];
  const float* Wqkv = (const float*)d_in[1];
  const float* bqkv = (const float*)d_in[2];
  const float* Wproj = (const float*)d_in[3];
  const float* bproj = (const float*)d_in[4];
  float* out = (float*)d_out;
  char* ws = (char*)d_ws;

  // workspace layout (44.6 MB), lifetime-based aliasing:
  //  [ 0..8M)   Xb (dead after qkv) -> Op0 ; [8..16M) Wqkt (dead after qkv) -> Op1
  //  [16..24M)  Qb (dead after attn) -> Ob ; [24..32M) Kb ; [32..40M) Vtb
  //  [40..42M)  Wpt ; [42..42.5M) lp
  u16* Xb   = (u16*)(ws);
  u16* Op   = (u16*)(ws);                 // Op0 @0, Op1 @ +4194304 elems
  u16* Wqkt = (u16*)(ws + 8388608);
  u16* Qb   = (u16*)(ws + 16777216);
  u16* Ob   = (u16*)(ws + 16777216);
  u16* Kb   = (u16*)(ws + 25165824);
  u16* Vtb  = (u16*)(ws + 33554432);
  u16* Wpt  = (u16*)(ws + 41943040);
  float* lp = (float*)(ws + 44040192);

  prep_kernel<<<8192, 256, 0, stream>>>(x, Xb, Wqkv, Wqkt, Wproj, Wpt);
  qkv_gemm_kernel<<<dim3(32, 24), 256, 0, stream>>>(Xb, Wqkt, bqkv, Qb, Kb, Vtb);
  attn_kernel<<<1024, 256, 0, stream>>>(Qb, Kb, Vtb, Op, lp);
  combine_kernel<<<4096, 128, 0, stream>>>(Op, lp, Ob);
  proj_gemm_kernel<<<dim3(32, 16), 256, 0, stream>>>(Ob, Wpt, bproj, out);
}